// Round 1
// baseline (417.170 us; speedup 1.0000x reference)
//
#include <hip/hip_runtime.h>
#include <stdint.h>

// Problem constants (fixed by the reference): B=8, H=W=64, C=256
#define CC 256
#define NN 4096           // H*W
#define MM 2048           // NN/2 (pooled)
#define BB 8
#define NROWS (BB*NN)     // 32768 query rows
#define PROWS (BB*MM)     // 16384 pooled rows

typedef __attribute__((ext_vector_type(8))) short   short8;   // 8 bf16 = one MFMA A/B frag
typedef __attribute__((ext_vector_type(4))) float   float4v;  // MFMA C/D frag

// bf16 round-to-nearest-even split helpers
__device__ __forceinline__ unsigned short f2bf(float f) {
    unsigned int u = __float_as_uint(f);
    u += 0x7fffu + ((u >> 16) & 1u);
    return (unsigned short)(u >> 16);
}
__device__ __forceinline__ float bf2f(unsigned short h) {
    return __uint_as_float(((unsigned int)h) << 16);
}

// ---------------------------------------------------------------------------
// proj_kernel: P = x[32768x256] @ [w_theta | w_phi | w_g]  (split-bf16 MFMA,
// 3-pass hi/lo -> ~2^-17 relative error). Epilogue:
//   cols 0..255   (theta): store hi/lo bf16, unpooled      -> th_hi/th_lo [row][c]
//   cols 256..511 (phi)  : maxpool row pairs, hi/lo bf16   -> ph_hi/ph_lo [prow][c]
//   cols 512..767 (g)    : maxpool row pairs, bf16, transposed -> g_t[b][c][m]
// Pooling is intra-lane: C/D layout row = quad*4 + reg, so rows (2i,2i+1) are
// adjacent regs of the same lane.
// ---------------------------------------------------------------------------
__global__ __launch_bounds__(256, 4) void proj_kernel(
    const float* __restrict__ x,
    const float* __restrict__ w_theta,
    const float* __restrict__ w_phi,
    const float* __restrict__ w_g,
    unsigned short* __restrict__ th_hi,
    unsigned short* __restrict__ th_lo,
    unsigned short* __restrict__ ph_hi,
    unsigned short* __restrict__ ph_lo,
    unsigned short* __restrict__ g_t)
{
    // W^T tile staged per K-half: [64 out-cols][128 k + pad to 136]
    // stride 136 shorts = 272 B: 16B-aligned rows, 68-word stride = 4 mod 32
    // -> only 2-way LDS aliasing on b128 reads (free per m136).
    __shared__ unsigned short wt_hi[64*136];
    __shared__ unsigned short wt_lo[64*136];

    const int tid  = threadIdx.x;
    const int r0   = blockIdx.x * 64;      // 512 row-blocks
    const int by   = blockIdx.y;           // 12 col-blocks of 64
    const int widx = by >> 2;              // 0=theta 1=phi 2=g
    const int wc0  = (by & 3) * 64;        // col offset within that w
    const float* wsel = (widx == 0) ? w_theta : (widx == 1) ? w_phi : w_g;

    const int wv   = tid >> 6;
    const int lane = tid & 63;
    const int quad = lane >> 4;
    const int l15  = lane & 15;
    const int arow = r0 + wv*16 + l15;     // this lane's A-frag row

    float4v acc[4];
    #pragma unroll
    for (int nf = 0; nf < 4; ++nf) acc[nf] = (float4v){0.f, 0.f, 0.f, 0.f};

    for (int h = 0; h < 2; ++h) {          // K in two halves of 128
        __syncthreads();
        {   // stage W^T (transpose + hi/lo split). coalesced global reads.
            const int j  = tid & 63;       // local out-col
            const int kb = tid >> 6;
            #pragma unroll 4
            for (int jj = 0; jj < 32; ++jj) {
                const int kl = kb + jj*4;  // local k 0..127
                float v = wsel[(size_t)(h*128 + kl)*CC + wc0 + j];
                unsigned short hi = f2bf(v);
                wt_hi[j*136 + kl] = hi;
                wt_lo[j*136 + kl] = f2bf(v - bf2f(hi));
            }
        }
        __syncthreads();

        #pragma unroll
        for (int ks = 0; ks < 4; ++ks) {   // 4 x K=32 MFMA steps per half
            // A-frag straight from global (16B contiguous per lane), split hi/lo
            const float* ap = x + (size_t)arow*CC + h*128 + ks*32 + quad*8;
            float4v a0 = *(const float4v*)ap;
            float4v a1 = *(const float4v*)(ap + 4);
            short8 a_hi, a_lo;
            #pragma unroll
            for (int jj = 0; jj < 4; ++jj) {
                unsigned short h0 = f2bf(a0[jj]);
                a_hi[jj]   = (short)h0; a_lo[jj]   = (short)f2bf(a0[jj] - bf2f(h0));
                unsigned short h1 = f2bf(a1[jj]);
                a_hi[4+jj] = (short)h1; a_lo[4+jj] = (short)f2bf(a1[jj] - bf2f(h1));
            }
            #pragma unroll
            for (int nf = 0; nf < 4; ++nf) {
                const int wrow = nf*16 + l15;
                short8 b_hi = *(const short8*)&wt_hi[wrow*136 + ks*32 + quad*8];
                short8 b_lo = *(const short8*)&wt_lo[wrow*136 + ks*32 + quad*8];
                acc[nf] = __builtin_amdgcn_mfma_f32_16x16x32_bf16(a_hi, b_hi, acc[nf], 0,0,0);
                acc[nf] = __builtin_amdgcn_mfma_f32_16x16x32_bf16(a_hi, b_lo, acc[nf], 0,0,0);
                acc[nf] = __builtin_amdgcn_mfma_f32_16x16x32_bf16(a_lo, b_hi, acc[nf], 0,0,0);
            }
        }
    }

    // epilogue: C/D layout row = rowbase + reg, col = wc0 + nf*16 + l15
    const int rowbase = r0 + wv*16 + quad*4;
    if (widx == 0) {                       // theta: unpooled hi/lo
        #pragma unroll
        for (int nf = 0; nf < 4; ++nf) {
            const int c = wc0 + nf*16 + l15;
            #pragma unroll
            for (int r = 0; r < 4; ++r) {
                float v = acc[nf][r];
                unsigned short hh = f2bf(v);
                size_t idx = (size_t)(rowbase + r)*CC + c;
                th_hi[idx] = hh;
                th_lo[idx] = f2bf(v - bf2f(hh));
            }
        }
    } else if (widx == 1) {                // phi: pool pairs, hi/lo
        #pragma unroll
        for (int nf = 0; nf < 4; ++nf) {
            const int c = wc0 + nf*16 + l15;
            #pragma unroll
            for (int rp = 0; rp < 2; ++rp) {
                float v = fmaxf(acc[nf][2*rp], acc[nf][2*rp+1]);
                const int prow = rowbase/2 + rp;   // rowbase even -> exact
                unsigned short hh = f2bf(v);
                size_t idx = (size_t)prow*CC + c;
                ph_hi[idx] = hh;
                ph_lo[idx] = f2bf(v - bf2f(hh));
            }
        }
    } else {                               // g: pool pairs, bf16, transposed
        #pragma unroll
        for (int nf = 0; nf < 4; ++nf) {
            const int c = wc0 + nf*16 + l15;
            #pragma unroll
            for (int rp = 0; rp < 2; ++rp) {
                float v = fmaxf(acc[nf][2*rp], acc[nf][2*rp+1]);
                const int prow = rowbase/2 + rp;   // global pooled row
                const int b = prow >> 11;          // /2048
                const int m = prow & 2047;
                g_t[(size_t)b*(CC*MM) + (size_t)c*MM + m] = f2bf(v);
            }
        }
    }
}

// ---------------------------------------------------------------------------
// attn_kernel: flash-style. Block = 64 queries (16 per wave), loops 64 tiles
// of 32 keys. S = theta@phi^T via 3-pass split-bf16 MFMA (logit err ~3e-3);
// online softmax in fp32; P -> bf16 -> LDS round-trip (C-layout -> A-layout);
// O += P@g via bf16 MFMA with g staged transposed for b128 B-frag reads.
// ---------------------------------------------------------------------------
__global__ __launch_bounds__(256, 2) void attn_kernel(
    const float* __restrict__ x,
    const unsigned short* __restrict__ th_hi,
    const unsigned short* __restrict__ th_lo,
    const unsigned short* __restrict__ ph_hi,
    const unsigned short* __restrict__ ph_lo,
    const unsigned short* __restrict__ g_t,
    float* __restrict__ out)
{
    // phi tile [32 keys][256 c] padded to 264 shorts/row (2-way-free reads)
    __shared__ unsigned short s_ph_hi[32*264];
    __shared__ unsigned short s_ph_lo[32*264];
    // g tile transposed [256 c][32 keys] padded to 40 shorts/row
    __shared__ unsigned short s_gt[256*40];
    // per-wave P scratch [16 q][32 keys] padded to 40 shorts/row
    __shared__ unsigned short s_p[4][16*40];

    const int tid  = threadIdx.x;
    const int q0   = blockIdx.x * 64;      // 512 blocks; block stays in one batch
    const int b    = q0 / NN;
    const int wv   = tid >> 6;
    const int lane = tid & 63;
    const int quad = lane >> 4;
    const int l15  = lane & 15;

    // preload theta A-frags (hi/lo) for this wave's 16 rows: 16B contiguous.
    short8 t_hi[8], t_lo[8];
    {
        const int row = q0 + wv*16 + l15;
        const unsigned short* bh = th_hi + (size_t)row*CC;
        const unsigned short* bl = th_lo + (size_t)row*CC;
        #pragma unroll
        for (int ks = 0; ks < 8; ++ks) {
            t_hi[ks] = *(const short8*)(bh + ks*32 + quad*8);
            t_lo[ks] = *(const short8*)(bl + ks*32 + quad*8);
        }
    }

    float4v O[16];
    #pragma unroll
    for (int ct = 0; ct < 16; ++ct) O[ct] = (float4v){0.f, 0.f, 0.f, 0.f};
    float m_i[4] = {-1e30f, -1e30f, -1e30f, -1e30f};
    float l_i[4] = {0.f, 0.f, 0.f, 0.f};

    const size_t phbase = (size_t)b * MM * CC;
    const size_t gtbase = (size_t)b * CC * MM;

    for (int kt = 0; kt < 64; ++kt) {
        const int key0 = kt * 32;
        __syncthreads();                   // prev tile's LDS reads complete
        {   // stage phi hi/lo [32][256] and g_t [256][32]
            const int i  = tid >> 3;               // key row 0..31
            const int cs = (tid & 7) * 32;         // 32-channel segment
            const unsigned short* sh = ph_hi + phbase + (size_t)(key0 + i)*CC + cs;
            const unsigned short* sl = ph_lo + phbase + (size_t)(key0 + i)*CC + cs;
            unsigned short* dh = &s_ph_hi[i*264 + cs];
            unsigned short* dl = &s_ph_lo[i*264 + cs];
            #pragma unroll
            for (int u = 0; u < 4; ++u) {
                *(uint4*)(dh + u*8) = *(const uint4*)(sh + u*8);
                *(uint4*)(dl + u*8) = *(const uint4*)(sl + u*8);
            }
            const unsigned short* sg = g_t + gtbase + (size_t)tid*MM + key0;
            unsigned short* dg = &s_gt[tid*40];
            #pragma unroll
            for (int u = 0; u < 4; ++u)
                *(uint4*)(dg + u*8) = *(const uint4*)(sg + u*8);
        }
        __syncthreads();

        // S tiles: two 16-key sub-tiles, 3-pass split accumulate
        float4v S0 = (float4v){0.f,0.f,0.f,0.f};
        float4v S1 = (float4v){0.f,0.f,0.f,0.f};
        #pragma unroll
        for (int ks = 0; ks < 8; ++ks) {
            short8 b0h = *(const short8*)&s_ph_hi[( 0 + l15)*264 + ks*32 + quad*8];
            short8 b0l = *(const short8*)&s_ph_lo[( 0 + l15)*264 + ks*32 + quad*8];
            short8 b1h = *(const short8*)&s_ph_hi[(16 + l15)*264 + ks*32 + quad*8];
            short8 b1l = *(const short8*)&s_ph_lo[(16 + l15)*264 + ks*32 + quad*8];
            S0 = __builtin_amdgcn_mfma_f32_16x16x32_bf16(t_hi[ks], b0h, S0, 0,0,0);
            S0 = __builtin_amdgcn_mfma_f32_16x16x32_bf16(t_hi[ks], b0l, S0, 0,0,0);
            S0 = __builtin_amdgcn_mfma_f32_16x16x32_bf16(t_lo[ks], b0h, S0, 0,0,0);
            S1 = __builtin_amdgcn_mfma_f32_16x16x32_bf16(t_hi[ks], b1h, S1, 0,0,0);
            S1 = __builtin_amdgcn_mfma_f32_16x16x32_bf16(t_hi[ks], b1l, S1, 0,0,0);
            S1 = __builtin_amdgcn_mfma_f32_16x16x32_bf16(t_lo[ks], b1h, S1, 0,0,0);
        }

        // online softmax. Row r lives in reg r across the 16 lanes of a quad.
        float p0[4], p1[4], al[4];
        #pragma unroll
        for (int r = 0; r < 4; ++r) {
            float v = fmaxf(S0[r], S1[r]);
            v = fmaxf(v, __shfl_xor(v, 1));
            v = fmaxf(v, __shfl_xor(v, 2));
            v = fmaxf(v, __shfl_xor(v, 4));
            v = fmaxf(v, __shfl_xor(v, 8));
            const float mn = fmaxf(m_i[r], v);
            al[r] = __expf(m_i[r] - mn);
            p0[r] = __expf(S0[r] - mn);
            p1[r] = __expf(S1[r] - mn);
            float s = p0[r] + p1[r];
            s += __shfl_xor(s, 1);
            s += __shfl_xor(s, 2);
            s += __shfl_xor(s, 4);
            s += __shfl_xor(s, 8);
            l_i[r] = l_i[r]*al[r] + s;
            m_i[r] = mn;
        }
        #pragma unroll
        for (int ct = 0; ct < 16; ++ct) {
            #pragma unroll
            for (int r = 0; r < 4; ++r) O[ct][r] *= al[r];
        }

        // P: C-layout -> LDS -> A-layout (per-wave region, intra-wave wait only)
        unsigned short* pw = &s_p[wv][0];
        #pragma unroll
        for (int r = 0; r < 4; ++r) {
            pw[(quad*4 + r)*40 + l15]      = f2bf(p0[r]);
            pw[(quad*4 + r)*40 + 16 + l15] = f2bf(p1[r]);
        }
        asm volatile("s_waitcnt lgkmcnt(0)" ::: "memory");
        short8 pfrag = *(const short8*)&s_p[wv][l15*40 + quad*8];

        // O += P @ g  (16 column tiles)
        #pragma unroll
        for (int ct = 0; ct < 16; ++ct) {
            short8 gfrag = *(const short8*)&s_gt[(ct*16 + l15)*40 + quad*8];
            O[ct] = __builtin_amdgcn_mfma_f32_16x16x32_bf16(pfrag, gfrag, O[ct], 0,0,0);
        }
    }

    // epilogue: y = O/l, out = x + y
    const int rowbase = q0 + wv*16 + quad*4;
    #pragma unroll
    for (int ct = 0; ct < 16; ++ct) {
        const int c = ct*16 + l15;
        #pragma unroll
        for (int r = 0; r < 4; ++r) {
            const size_t idx = (size_t)(rowbase + r)*CC + c;
            out[idx] = x[idx] + O[ct][r] / l_i[r];
        }
    }
}

// ---------------------------------------------------------------------------
extern "C" void kernel_launch(void* const* d_in, const int* in_sizes, int n_in,
                              void* d_out, int out_size, void* d_ws, size_t ws_size,
                              hipStream_t stream) {
    const float* x       = (const float*)d_in[0];
    const float* w_theta = (const float*)d_in[1];
    const float* w_phi   = (const float*)d_in[2];
    const float* w_g     = (const float*)d_in[3];
    float* out = (float*)d_out;

    // workspace layout (56 MB total; assumes ws_size >= 58,720,256 B)
    unsigned short* th_hi = (unsigned short*)d_ws;
    unsigned short* th_lo = th_hi + (size_t)NROWS*CC;   // +16.78 MB
    unsigned short* ph_hi = th_lo + (size_t)NROWS*CC;   // +16.78 MB
    unsigned short* ph_lo = ph_hi + (size_t)PROWS*CC;   // + 8.39 MB
    unsigned short* g_t   = ph_lo + (size_t)PROWS*CC;   // + 8.39 MB (-> 56 MB)

    dim3 gproj(NROWS/64, 12);
    proj_kernel<<<gproj, 256, 0, stream>>>(x, w_theta, w_phi, w_g,
                                           th_hi, th_lo, ph_hi, ph_lo, g_t);
    attn_kernel<<<NROWS/64, 256, 0, stream>>>(x, th_hi, th_lo, ph_hi, ph_lo,
                                              g_t, out);
}

// Round 3
// 338.855 us; speedup vs baseline: 1.2311x; 1.2311x over previous
//
#include <hip/hip_runtime.h>
#include <stdint.h>

// Problem constants (fixed by the reference): B=8, H=W=64, C=256
#define CC 256
#define NN 4096           // H*W
#define MM 2048           // NN/2 (pooled)
#define BB 8
#define NROWS (BB*NN)     // 32768 query rows
#define PROWS (BB*MM)     // 16384 pooled rows

typedef __attribute__((ext_vector_type(8))) short    short8;   // 8 bf16
typedef __attribute__((ext_vector_type(8))) _Float16 half8;    // 8 fp16
typedef __attribute__((ext_vector_type(4))) float    float4v;

__device__ __forceinline__ unsigned short f2bf(float f) {
    unsigned int u = __float_as_uint(f);
    u += 0x7fffu + ((u >> 16) & 1u);
    return (unsigned short)(u >> 16);
}
__device__ __forceinline__ float bf2f(unsigned short h) {
    return __uint_as_float(((unsigned int)h) << 16);
}
__device__ __forceinline__ unsigned short f2h(float f) {
    union { _Float16 h; unsigned short u; } cv; cv.h = (_Float16)f; return cv.u;
}
__device__ __forceinline__ float h2f(unsigned short u) {
    union { _Float16 h; unsigned short u; } cv; cv.u = u; return (float)cv.h;
}

// ---------------------------------------------------------------------------
// wsplit: transpose + bf16 hi/lo split the three 256x256 weights once.
// wT_hi/wT_lo layout: [widx][outcol][k]  (MFMA B-frags 16B contiguous)
// ---------------------------------------------------------------------------
__global__ void wsplit_kernel(const float* __restrict__ w_theta,
                              const float* __restrict__ w_phi,
                              const float* __restrict__ w_g,
                              unsigned short* __restrict__ wT_hi,
                              unsigned short* __restrict__ wT_lo)
{
    __shared__ float tile[64][65];
    const int widx = blockIdx.z;
    const int kt = blockIdx.x, ct = blockIdx.y;
    const float* w = (widx == 0) ? w_theta : (widx == 1) ? w_phi : w_g;
    const int t  = threadIdx.x;
    const int tc = t & 63, tr = t >> 6;
    #pragma unroll
    for (int i = 0; i < 16; ++i) {
        const int lk = tr*16 + i;
        tile[lk][tc] = w[(size_t)(kt*64 + lk)*CC + ct*64 + tc];
    }
    __syncthreads();
    #pragma unroll
    for (int i = 0; i < 16; ++i) {
        const int lc = tr*16 + i;
        float v = tile[tc][lc];
        const int c = ct*64 + lc, k = kt*64 + tc;
        unsigned short hh = f2bf(v);
        size_t o = ((size_t)widx*CC + c)*CC + k;
        wT_hi[o] = hh;
        wT_lo[o] = f2bf(v - bf2f(hh));
    }
}

// ---------------------------------------------------------------------------
// proj_kernel v3: each block computes a 64-row x 64-col slice of ALL THREE
// projections (x staged A-frags reused 3x; x HBM traffic 4x not 12x).
// Internal GEMM: split-bf16 3-pass (proven ~2^-17 rel).
// Outputs: theta -> fp16 hi/lo (for fp16 S MFMA); phi -> maxpool fp16;
//          g -> maxpool bf16 transposed g_t[b][c][m] (for PV bf16 MFMA).
// ---------------------------------------------------------------------------
__global__ __launch_bounds__(256, 4) void proj_kernel(
    const float* __restrict__ x,
    const unsigned short* __restrict__ wT_hi,
    const unsigned short* __restrict__ wT_lo,
    unsigned short* __restrict__ th_hi,
    unsigned short* __restrict__ th_lo,
    unsigned short* __restrict__ ph,
    unsigned short* __restrict__ g_t)
{
    __shared__ unsigned short wt_hi[64*136];   // [64 cols][128 k + pad]
    __shared__ unsigned short wt_lo[64*136];

    const int tid  = threadIdx.x;
    const int r0   = blockIdx.x * 64;          // 512 row-blocks
    const int wc0  = blockIdx.y * 64;          // 4 col-blocks
    const int wv   = tid >> 6;
    const int lane = tid & 63;
    const int quad = lane >> 4;
    const int l15  = lane & 15;
    const int arow = r0 + wv*16 + l15;

    float4v acc[3][4];
    #pragma unroll
    for (int w = 0; w < 3; ++w)
        #pragma unroll
        for (int nf = 0; nf < 4; ++nf) acc[w][nf] = (float4v){0.f,0.f,0.f,0.f};

    for (int h = 0; h < 2; ++h) {
        // A-frags for this K-half, split once, reused for all 3 weights
        short8 a_hi[4], a_lo[4];
        #pragma unroll
        for (int ks = 0; ks < 4; ++ks) {
            const float* ap = x + (size_t)arow*CC + h*128 + ks*32 + quad*8;
            float4v a0 = *(const float4v*)ap;
            float4v a1 = *(const float4v*)(ap + 4);
            #pragma unroll
            for (int jj = 0; jj < 4; ++jj) {
                unsigned short h0 = f2bf(a0[jj]);
                a_hi[ks][jj]   = (short)h0; a_lo[ks][jj]   = (short)f2bf(a0[jj] - bf2f(h0));
                unsigned short h1 = f2bf(a1[jj]);
                a_hi[ks][4+jj] = (short)h1; a_lo[ks][4+jj] = (short)f2bf(a1[jj] - bf2f(h1));
            }
        }
        for (int w = 0; w < 3; ++w) {
            __syncthreads();               // protect previous tile's reads
            {   // stage pre-split W^T slice [64 cols][128 k]
                const int j    = tid & 63;
                const int kseg = tid >> 6;
                const size_t base = ((size_t)w*CC + wc0 + j)*CC + h*128 + kseg*32;
                const unsigned short* sh = wT_hi + base;
                const unsigned short* sl = wT_lo + base;
                unsigned short* dh = &wt_hi[j*136 + kseg*32];
                unsigned short* dl = &wt_lo[j*136 + kseg*32];
                #pragma unroll
                for (int u = 0; u < 4; ++u) {
                    *(uint4*)(dh + u*8) = *(const uint4*)(sh + u*8);
                    *(uint4*)(dl + u*8) = *(const uint4*)(sl + u*8);
                }
            }
            __syncthreads();
            #pragma unroll
            for (int ks = 0; ks < 4; ++ks) {
                #pragma unroll
                for (int nf = 0; nf < 4; ++nf) {
                    const int wrow = nf*16 + l15;
                    short8 b_hi = *(const short8*)&wt_hi[wrow*136 + ks*32 + quad*8];
                    short8 b_lo = *(const short8*)&wt_lo[wrow*136 + ks*32 + quad*8];
                    acc[w][nf] = __builtin_amdgcn_mfma_f32_16x16x32_bf16(a_hi[ks], b_hi, acc[w][nf], 0,0,0);
                    acc[w][nf] = __builtin_amdgcn_mfma_f32_16x16x32_bf16(a_hi[ks], b_lo, acc[w][nf], 0,0,0);
                    acc[w][nf] = __builtin_amdgcn_mfma_f32_16x16x32_bf16(a_lo[ks], b_hi, acc[w][nf], 0,0,0);
                }
            }
        }
    }

    const int rowbase = r0 + wv*16 + quad*4;
    // theta: unpooled, fp16 hi/lo
    #pragma unroll
    for (int nf = 0; nf < 4; ++nf) {
        const int c = wc0 + nf*16 + l15;
        #pragma unroll
        for (int r = 0; r < 4; ++r) {
            float v = acc[0][nf][r];
            unsigned short hh = f2h(v);
            size_t idx = (size_t)(rowbase + r)*CC + c;
            th_hi[idx] = hh;
            th_lo[idx] = f2h(v - h2f(hh));
        }
    }
    // phi: pool row pairs (C/D rows 2i,2i+1 are adjacent regs), fp16
    #pragma unroll
    for (int nf = 0; nf < 4; ++nf) {
        const int c = wc0 + nf*16 + l15;
        #pragma unroll
        for (int rp = 0; rp < 2; ++rp) {
            float v = fmaxf(acc[1][nf][2*rp], acc[1][nf][2*rp+1]);
            const int prow = rowbase/2 + rp;      // rowbase even -> exact
            ph[(size_t)prow*CC + c] = f2h(v);
        }
    }
    // g: pool, bf16, transposed g_t[b][c][m]
    #pragma unroll
    for (int nf = 0; nf < 4; ++nf) {
        const int c = wc0 + nf*16 + l15;
        #pragma unroll
        for (int rp = 0; rp < 2; ++rp) {
            float v = fmaxf(acc[2][nf][2*rp], acc[2][nf][2*rp+1]);
            const int prow = rowbase/2 + rp;
            const int b = prow >> 11;
            const int m = prow & 2047;
            g_t[((size_t)b*CC + c)*MM + m] = f2bf(v);
        }
    }
}

// ---------------------------------------------------------------------------
// phimean: per-batch column mean of phi (fp32), for the per-row softmax shift.
// grid 64 = 8 batches x 8 row-chunks; atomicAdd partials (phbar pre-zeroed).
// ---------------------------------------------------------------------------
__global__ void phimean_kernel(const unsigned short* __restrict__ ph,
                               float* __restrict__ phbar)
{
    const int b = blockIdx.x >> 3, chunk = blockIdx.x & 7;
    const int c = threadIdx.x;
    const size_t base = ((size_t)b*MM + chunk*256)*CC + c;
    float s = 0.f;
    for (int r = 0; r < 256; ++r) s += h2f(ph[base + (size_t)r*CC]);
    atomicAdd(&phbar[b*CC + c], s * (1.0f/MM));
}

// ---------------------------------------------------------------------------
// attn_kernel v3: shift softmax with per-row shift = theta.phibar + 128,
// exp-arg clamped to [-85, 85] -> every p >= e^-85 (bf16-representable),
// accl > 0 structurally => NaN impossible. No shuffles/rescale in the loop.
// S: fp16 2-pass (theta hi/lo x phi), PV: bf16. Row-sum l via ones-MFMA.
// ---------------------------------------------------------------------------
__global__ __launch_bounds__(256, 2) void attn_kernel(
    const float* __restrict__ x,
    const unsigned short* __restrict__ th_hi,
    const unsigned short* __restrict__ th_lo,
    const unsigned short* __restrict__ ph,
    const unsigned short* __restrict__ g_t,
    const float* __restrict__ phbar,
    float* __restrict__ out)
{
    __shared__ unsigned short s_ph[32*264];    // phi tile fp16, padded rows
    __shared__ unsigned short s_gt[256*40];    // g tile bf16, transposed, padded
    __shared__ unsigned short s_p[4][16*40];   // per-wave P scratch (bf16)

    const int tid  = threadIdx.x;
    const int q0   = blockIdx.x * 64;
    const int b    = q0 >> 12;
    const int wv   = tid >> 6;
    const int lane = tid & 63;
    const int quad = lane >> 4;
    const int l15  = lane & 15;

    // theta A-frags (fp16 hi/lo) for this wave's 16 rows
    half8 t_hi[8], t_lo[8];
    {
        const unsigned short* bh = th_hi + (size_t)(q0 + wv*16 + l15)*CC;
        const unsigned short* bl = th_lo + (size_t)(q0 + wv*16 + l15)*CC;
        #pragma unroll
        for (int ks = 0; ks < 8; ++ks) {
            t_hi[ks] = *(const half8*)(bh + ks*32 + quad*8);
            t_lo[ks] = *(const half8*)(bl + ks*32 + quad*8);
        }
    }

    // per-row shift = theta . phibar  (+128), moved to C-layout rows via shfl
    float sh128[4];
    {
        float sp = 0.f;
        #pragma unroll
        for (int ks = 0; ks < 8; ++ks) {
            const int k0 = ks*32 + quad*8;
            float4v m0 = *(const float4v*)&phbar[b*CC + k0];
            float4v m1 = *(const float4v*)&phbar[b*CC + k0 + 4];
            #pragma unroll
            for (int j = 0; j < 4; ++j) {
                sp += (float)t_hi[ks][j]   * m0[j];
                sp += (float)t_hi[ks][4+j] * m1[j];
            }
        }
        sp += __shfl_xor(sp, 16);
        sp += __shfl_xor(sp, 32);          // all lanes: full dot for row l15
        #pragma unroll
        for (int r = 0; r < 4; ++r)
            sh128[r] = __shfl(sp, quad*4 + r) + 128.f;
    }

    float4v O[16];
    #pragma unroll
    for (int ct = 0; ct < 16; ++ct) O[ct] = (float4v){0.f,0.f,0.f,0.f};
    float4v accl = (float4v){0.f,0.f,0.f,0.f};

    short8 ones;
    #pragma unroll
    for (int j = 0; j < 8; ++j) ones[j] = (short)0x3F80;   // bf16 1.0

    const size_t phbase = (size_t)b * MM * CC;
    const size_t gtbase = (size_t)b * CC * MM;

    for (int kt = 0; kt < 64; ++kt) {
        const int key0 = kt * 32;
        __syncthreads();
        {   // stage phi [32][256] fp16 and g_t [256][32] bf16
            const int i  = tid >> 3;
            const int cs = (tid & 7) * 32;
            const unsigned short* sh = ph + phbase + (size_t)(key0 + i)*CC + cs;
            unsigned short* dh = &s_ph[i*264 + cs];
            #pragma unroll
            for (int u = 0; u < 4; ++u)
                *(uint4*)(dh + u*8) = *(const uint4*)(sh + u*8);
            const unsigned short* sg = g_t + gtbase + (size_t)tid*MM + key0;
            unsigned short* dg = &s_gt[tid*40];
            #pragma unroll
            for (int u = 0; u < 4; ++u)
                *(uint4*)(dg + u*8) = *(const uint4*)(sg + u*8);
        }
        __syncthreads();

        // S = theta @ phi^T, fp16 2-pass (hi + lo)
        float4v S0 = (float4v){0.f,0.f,0.f,0.f};
        float4v S1 = (float4v){0.f,0.f,0.f,0.f};
        #pragma unroll
        for (int ks = 0; ks < 8; ++ks) {
            half8 b0 = *(const half8*)&s_ph[( 0 + l15)*264 + ks*32 + quad*8];
            half8 b1 = *(const half8*)&s_ph[(16 + l15)*264 + ks*32 + quad*8];
            S0 = __builtin_amdgcn_mfma_f32_16x16x32_f16(t_hi[ks], b0, S0, 0,0,0);
            S1 = __builtin_amdgcn_mfma_f32_16x16x32_f16(t_hi[ks], b1, S1, 0,0,0);
            S0 = __builtin_amdgcn_mfma_f32_16x16x32_f16(t_lo[ks], b0, S0, 0,0,0);
            S1 = __builtin_amdgcn_mfma_f32_16x16x32_f16(t_lo[ks], b1, S1, 0,0,0);
        }

        // p = exp(clamp(S - shift, -85, 85)) -> bf16 (no row reductions)
        unsigned short* pw = &s_p[wv][0];
        #pragma unroll
        for (int r = 0; r < 4; ++r) {
            float a0 = fminf(fmaxf(S0[r] - sh128[r], -85.f), 85.f);
            float a1 = fminf(fmaxf(S1[r] - sh128[r], -85.f), 85.f);
            pw[(quad*4 + r)*40 + l15]      = f2bf(__expf(a0));
            pw[(quad*4 + r)*40 + 16 + l15] = f2bf(__expf(a1));
        }
        asm volatile("s_waitcnt lgkmcnt(0)" ::: "memory");
        short8 pfrag = *(const short8*)&s_p[wv][l15*40 + quad*8];

        // row-sum l via ones-column MFMA; O += P @ g
        accl = __builtin_amdgcn_mfma_f32_16x16x32_bf16(pfrag, ones, accl, 0,0,0);
        #pragma unroll
        for (int ct = 0; ct < 16; ++ct) {
            short8 gf = *(const short8*)&s_gt[(ct*16 + l15)*40 + quad*8];
            O[ct] = __builtin_amdgcn_mfma_f32_16x16x32_bf16(pfrag, gf, O[ct], 0,0,0);
        }
    }

    // epilogue: y = O/l, out = x + y
    float rl[4];
    #pragma unroll
    for (int r = 0; r < 4; ++r) rl[r] = 1.0f / accl[r];
    const int rowbase = q0 + wv*16 + quad*4;
    #pragma unroll
    for (int ct = 0; ct < 16; ++ct) {
        const int c = ct*16 + l15;
        #pragma unroll
        for (int r = 0; r < 4; ++r) {
            const size_t idx = (size_t)(rowbase + r)*CC + c;
            out[idx] = x[idx] + O[ct][r] * rl[r];
        }
    }
}

// ---------------------------------------------------------------------------
extern "C" void kernel_launch(void* const* d_in, const int* in_sizes, int n_in,
                              void* d_out, int out_size, void* d_ws, size_t ws_size,
                              hipStream_t stream) {
    const float* x       = (const float*)d_in[0];
    const float* w_theta = (const float*)d_in[1];
    const float* w_phi   = (const float*)d_in[2];
    const float* w_g     = (const float*)d_in[3];
    float* out = (float*)d_out;

    // workspace (~51.1 MB; round-1 verified ws >= 56 MB)
    unsigned short* th_hi = (unsigned short*)d_ws;                 // fp16 16.78 MB
    unsigned short* th_lo = th_hi + (size_t)NROWS*CC;              // fp16 16.78 MB
    unsigned short* ph    = th_lo + (size_t)NROWS*CC;              // fp16  8.39 MB
    unsigned short* g_t   = ph    + (size_t)PROWS*CC;              // bf16  8.39 MB
    unsigned short* wT_hi = g_t   + (size_t)PROWS*CC;              // bf16  0.39 MB
    unsigned short* wT_lo = wT_hi + (size_t)3*CC*CC;               // bf16  0.39 MB
    float*          phbar = (float*)(wT_lo + (size_t)3*CC*CC);     // fp32  8 KB

    hipMemsetAsync(phbar, 0, BB*CC*sizeof(float), stream);
    wsplit_kernel<<<dim3(4,4,3), 256, 0, stream>>>(w_theta, w_phi, w_g, wT_hi, wT_lo);
    proj_kernel<<<dim3(NROWS/64, 4), 256, 0, stream>>>(x, wT_hi, wT_lo,
                                                       th_hi, th_lo, ph, g_t);
    phimean_kernel<<<64, 256, 0, stream>>>(ph, phbar);
    attn_kernel<<<NROWS/64, 256, 0, stream>>>(x, th_hi, th_lo, ph, g_t, phbar, out);
}